// Round 4
// baseline (177.961 us; speedup 1.0000x reference)
//
#include <hip/hip_runtime.h>

#define N_NODES 8192
#define E_EDGES 16384
#define S_SEG   16
#define EXT     64
#define P_PATHS 2048
#define ROW     1024            // S_SEG*EXT floats per row

typedef _Float16 f16x8  __attribute__((ext_vector_type(8)));
typedef _Float16 f16x4  __attribute__((ext_vector_type(4)));
typedef _Float16 half2v __attribute__((ext_vector_type(2)));
typedef float    f32x4  __attribute__((ext_vector_type(4)));

// ---- workspace layout (bytes) ----
#define WS_CMAT  0        // f16[4096]  8 KB  (only workspace use)

// ---------------------------------------------------------------------------
// K1: block 0 builds the dense path-coefficient matrix Cmat[k][i*16+j] (f16);
//     blocks 1..2048 zero the 33.5 MB output (atomic background + deg-0 rows).
// ---------------------------------------------------------------------------
__global__ __launch_bounds__(256) void prep_zero(
        const int* __restrict__ pidx, const float* __restrict__ pcoef,
        _Float16* __restrict__ Cmat, float* __restrict__ out) {
    const int tid = threadIdx.x;
    if (blockIdx.x == 0) {
        __shared__ float sC[S_SEG * S_SEG * S_SEG];
        for (int i = tid; i < 4096; i += 256) sC[i] = 0.f;
        __syncthreads();
        for (int p = tid; p < P_PATHS; p += 256) {
            const int i = pidx[3 * p + 0];
            const int j = pidx[3 * p + 1];
            const int k = pidx[3 * p + 2];
            atomicAdd(&sC[(k * S_SEG + i) * S_SEG + j], pcoef[p]);
        }
        __syncthreads();
        for (int i = tid; i < 4096; i += 256) Cmat[i] = (_Float16)sC[i];
    } else {
        // 2048 blocks x 4096 floats = 8192*1024 floats total
        const float4 z = {0.f, 0.f, 0.f, 0.f};
        float* ob = out + (size_t)(blockIdx.x - 1) * 4096 + tid * 4;
#pragma unroll
        for (int r = 0; r < 4; ++r) *(float4*)(ob + r * 1024) = z;
    }
}

// ---------------------------------------------------------------------------
// K2: one wave per edge, NATURAL edge order (y fully sequential, x gathered
// through L2/L3). Per-edge tile out_e[k,c] = sum_{i,j} C[k,i,j] x[i,c] y[j,c]
// via fp16 MFMA (verified body from rounds 2-3), then 16 wave-wide f32
// atomicAdds into out[idx_out[e]]. No sort, no scan, no extra passes.
// ---------------------------------------------------------------------------
__global__ __launch_bounds__(256) void edge_atomic(
        const float* __restrict__ x, const float* __restrict__ y,
        const _Float16* __restrict__ Cmat,
        const int* __restrict__ idx_in, const int* __restrict__ idx_out,
        float* __restrict__ out) {
    __shared__ __attribute__((aligned(16))) _Float16 sx_all[4][ROW];   // 2KB/wave
    __shared__ __attribute__((aligned(16))) half2v   sy_all[4][512];   // 2KB/wave

    const int tid  = threadIdx.x;
    const int lane = tid & 63;
    const int wv   = tid >> 6;
    _Float16* sxh = sx_all[wv];
    half2v*   syp = sy_all[wv];

    const int e  = blockIdx.x * 4 + wv;     // 0..16383
    const int xr = idx_in[e];
    const int nd = idx_out[e];

    const int quad = lane >> 4;
    const int m    = lane & 15;
    const int jb2  = (quad & 1) * 4;
    const int ih   = quad >> 1;
    const int jp   = lane >> 3;          // 0..7
    const int cq   = (lane & 7) * 8;     // 8 cols per lane

    // A fragments: afrag[kk][jr] = Cmat[m][kk*32 + quad*8 + jr]
    f16x8 afrag[8];
    {
        const _Float16* basep = Cmat + m * 256 + quad * 8;
#pragma unroll
        for (int kk = 0; kk < 8; ++kk) afrag[kk] = *(const f16x8*)(basep + kk * 32);
    }

    const float* xp = x + (size_t)xr * ROW;
    const float* yp = y + (size_t)e  * ROW;
    float4 xb[4], yb[4];
#pragma unroll
    for (int k4 = 0; k4 < 4; ++k4)
        xb[k4] = *(const float4*)(xp + k4 * 256 + lane * 4);
    yb[0] = *(const float4*)(yp + (2 * jp)     * EXT + cq);
    yb[1] = *(const float4*)(yp + (2 * jp)     * EXT + cq + 4);
    yb[2] = *(const float4*)(yp + (2 * jp + 1) * EXT + cq);
    yb[3] = *(const float4*)(yp + (2 * jp + 1) * EXT + cq + 4);

    // stage -> f16 LDS (wave-private, no barriers)
#pragma unroll
    for (int k4 = 0; k4 < 4; ++k4) {
        const float4 v = xb[k4];
        *(f16x4*)(sxh + k4 * 256 + lane * 4) =
            f16x4{(_Float16)v.x, (_Float16)v.y, (_Float16)v.z, (_Float16)v.w};
    }
    {
        const float4 a0 = yb[0], a1 = yb[1];
        const float4 c0 = yb[2], c1 = yb[3];
        *(f16x8*)(syp + jp * 64 + cq) =
            f16x8{(_Float16)a0.x, (_Float16)c0.x, (_Float16)a0.y, (_Float16)c0.y,
                  (_Float16)a0.z, (_Float16)c0.z, (_Float16)a0.w, (_Float16)c0.w};
        *(f16x8*)(syp + jp * 64 + cq + 4) =
            f16x8{(_Float16)a1.x, (_Float16)c1.x, (_Float16)a1.y, (_Float16)c1.y,
                  (_Float16)a1.z, (_Float16)c1.z, (_Float16)a1.w, (_Float16)c1.w};
    }

    f32x4 acc[4];
#pragma unroll
    for (int ct = 0; ct < 4; ++ct) acc[ct] = f32x4{0.f, 0.f, 0.f, 0.f};

    // 4 col-tiles x 8 K-steps of mfma_f32_16x16x32_f16
#pragma unroll
    for (int ct = 0; ct < 4; ++ct) {
        const int c = ct * 16 + m;
        half2v ypk[4];
#pragma unroll
        for (int r = 0; r < 4; ++r) ypk[r] = syp[(jb2 + r) * 64 + c];
#pragma unroll
        for (int kk = 0; kk < 8; ++kk) {
            const _Float16 xh = sxh[(2 * kk + ih) * EXT + c];
            const half2v hx = {xh, xh};
            const half2v b0 = hx * ypk[0];
            const half2v b1 = hx * ypk[1];
            const half2v b2 = hx * ypk[2];
            const half2v b3 = hx * ypk[3];
            const f16x8 bfrag = {b0[0], b0[1], b1[0], b1[1],
                                 b2[0], b2[1], b3[0], b3[1]};
            acc[ct] = __builtin_amdgcn_mfma_f32_16x16x32_f16(
                          afrag[kk], bfrag, acc[ct], 0, 0, 0);
        }
    }

    // epilogue: 16 wave-wide fire-and-forget f32 atomic adds.
    // element (ct,r): row = quad*4+r, col = ct*16+m  ->  each instruction
    // covers 4 contiguous 64B chunks across the wave.
    float* ob = out + (size_t)nd * ROW;
#pragma unroll
    for (int ct = 0; ct < 4; ++ct)
#pragma unroll
        for (int r = 0; r < 4; ++r)
            atomicAdd(ob + (quad * 4 + r) * EXT + ct * 16 + m, acc[ct][r]);
}

// ---------------------------------------------------------------------------
extern "C" void kernel_launch(void* const* d_in, const int* in_sizes, int n_in,
                              void* d_out, int out_size, void* d_ws, size_t ws_size,
                              hipStream_t stream) {
    const float* x       = (const float*)d_in[0];
    const float* y       = (const float*)d_in[1];
    const int*   idx_in  = (const int*)d_in[2];
    const int*   idx_out = (const int*)d_in[3];
    const int*   pidx    = (const int*)d_in[4];
    const float* pcoef   = (const float*)d_in[5];
    float* out           = (float*)d_out;

    _Float16* Cmat = (_Float16*)((char*)d_ws + WS_CMAT);

    prep_zero<<<1 + N_NODES * ROW / 4096, 256, 0, stream>>>(pidx, pcoef, Cmat, out);
    edge_atomic<<<E_EDGES / 4, 256, 0, stream>>>(x, y, Cmat, idx_in, idx_out, out);
}